// Round 19
// baseline (4824.015 us; speedup 1.0000x reference)
//
#include <hip/hip_runtime.h>
#include <cstdint>
#include <cstddef>

// Round 19: revert R18's XCD experiment (deadlock: relaxed id-publish race ->
// divergent protocol choice; mixed workgroup/agent RMWs on one counter never
// converge). Base = R17 (best passing, 4805us). One change: grid barrier's
// 16 serialized fetch_adds on ONE cacheline -> per-block 64B-padded step
// flags; tid0 stores s+1 (after the h'-draining syncthreads, same ordering
// guarantee as R17), threads 0..15 poll 16 flags in parallel (1 RTT/round).

typedef unsigned short bf_t;
typedef __attribute__((ext_vector_type(8))) short bf16x8;
typedef __attribute__((ext_vector_type(4))) float f32x4;

#define DEVI __device__ __forceinline__
DEVI float bf2f(bf_t u){ return __uint_as_float(((unsigned)u)<<16); }
DEVI bf_t  f2bf(float f){ unsigned u=__float_as_uint(f); return (bf_t)((u + 0x7FFFu + ((u>>16)&1u))>>16); }
DEVI float sigx(float x){ return __builtin_amdgcn_rcpf(1.0f + __builtin_amdgcn_exp2f(-1.44269504f*x)); }
DEVI float tanx(float x){ return 2.0f*__builtin_amdgcn_rcpf(1.0f + __builtin_amdgcn_exp2f(-2.88539008f*x)) - 1.0f; }

__global__ void k_dbg(float* out, unsigned mb){ out[0] = (float)mb; }

// ===== weight prep =====
__global__ __launch_bounds__(256) void k_prep_charm(const float* __restrict__ wcf,
    const float* __restrict__ wcb, bf_t* __restrict__ wct){
  int i = blockIdx.x*256 + threadIdx.x;
  if (i >= 2*400*160) return;
  int kk = i % 160; int r = i / 160;
  int np = r % 400; int dir = r / 400;
  int u = np >> 2, g = np & 3;
  const float* w = dir ? wcb : wcf;
  wct[i] = (kk < 150) ? f2bf(w[kk*400 + g*100 + u]) : (bf_t)0;
}
__global__ __launch_bounds__(256) void k_prep_wrec(const float* __restrict__ wwf,
    const float* __restrict__ wwb, bf_t* __restrict__ wrg){
  int i = blockIdx.x*256 + threadIdx.x;
  if (i >= 2*2048*512) return;
  int k = i & 511; int np = (i >> 9) & 2047; int dir = i >> 20;
  int c = np >> 2, g = np & 3;
  const float* w = dir ? wwb : wwf;
  wrg[i] = f2bf(w[(size_t)(500 + k)*2048 + g*512 + c]);
}
__global__ __launch_bounds__(256) void k_prep_trec(const float* __restrict__ wo,
    bf_t* __restrict__ wog){
  int i = blockIdx.x*256 + threadIdx.x;
  if (i >= 2048*512) return;
  int k = i & 511; int np = i >> 9;
  int c = np >> 2, g = np & 3;
  wog[i] = f2bf(wo[(size_t)(1024 + k)*2048 + g*512 + c]);
}
__global__ __launch_bounds__(256) void k_prep_wx(const float* __restrict__ wwf,
    const float* __restrict__ wwb, bf_t* __restrict__ wx){
  int i = blockIdx.x*256 + threadIdx.x;
  if (i >= 2*2048*512) return;
  int k = i & 511; int r = i >> 9;
  int np = r & 2047; int dir = r >> 11;
  int c = np >> 2, g = np & 3;
  const float* w = dir ? wwb : wwf;
  wx[i] = (k < 500) ? f2bf(w[(size_t)k*2048 + g*512 + c]) : (bf_t)0;
}
__global__ __launch_bounds__(256) void k_prep_wxt(const float* __restrict__ wo,
    bf_t* __restrict__ wxt){
  int i = blockIdx.x*256 + threadIdx.x;
  if (i >= 2048*1024) return;
  int k = i & 1023; int np = i >> 10;
  int c = np >> 2, g = np & 3;
  wxt[i] = f2bf(wo[(size_t)k*2048 + g*512 + c]);
}
__global__ __launch_bounds__(256) void k_prep_bias(const float* __restrict__ bwf,
    const float* __restrict__ bwb, const float* __restrict__ bo,
    float* __restrict__ bpf, float* __restrict__ bpb, float* __restrict__ bpt){
  int np = blockIdx.x*256 + threadIdx.x;
  if (np >= 2048) return;
  int c = np >> 2, g = np & 3;
  bpf[np] = bwf[g*512 + c];
  bpb[np] = bwb[g*512 + c];
  bpt[np] = bo[g*512 + c];
}
__global__ __launch_bounds__(256) void k_ridx(const int* __restrict__ lens,
    int* __restrict__ ridxb){
  int b = blockIdx.x, t = threadIdx.x;
  int L = lens[b];
  int tin = (t < L) ? (L - 1 - t) : t;
  ridxb[b*256 + t] = b*256 + tin;
}

// ===== char BiLSTM v3: persistent, MFMA, weights in registers =====
DEVI int aslot(int s, int kk){
  return (((kk >> 5)*4 + ((kk >> 3) & 3))*16 + s)*8 + (kk & 7);
}
__global__ __launch_bounds__(512) void k_charm(const float* __restrict__ subwords,
    const int* __restrict__ slens, const bf_t* __restrict__ wct,
    const float* __restrict__ bcf, const float* __restrict__ bcb,
    bf_t* __restrict__ rep){
  const int dir = blockIdx.y;
  const int tid = threadIdx.x;
  const int w = tid >> 6, lane = tid & 63;
  const int l16 = lane & 15, lk = lane >> 4;

  __shared__ __align__(16) bf_t abuf[2560];
  __shared__ float zs[16][409];
  __shared__ float bs[400];
  __shared__ int lens[16];

  {
    const float* bc = dir ? bcb : bcf;
    for (int i = tid; i < 400; i += 512) bs[i] = bc[(i & 3)*100 + (i >> 2)];
  }

  const bf_t* wctd = wct + (size_t)dir*400*160;
  int jt[4];
  bf16x8 breg[4][5];
#pragma unroll
  for (int jj = 0; jj < 4; jj++) {
    int j = w + jj*8; jt[jj] = j;
    int js = (j < 25) ? j : 0;
#pragma unroll
    for (int ks = 0; ks < 5; ks++)
      breg[jj][ks] = *(const bf16x8*)(wctd + (size_t)(js*16 + l16)*160 + ks*32 + lk*8);
  }

  int si[2], ki[2]; bool vr[2];
#pragma unroll
  for (int r = 0; r < 2; r++) {
    int i = tid + r*512;
    vr[r] = (i < 800);
    si[r] = vr[r] ? (i / 50) : 0;
    ki[r] = vr[r] ? (i - si[r]*50) : 0;
  }

  for (int g = 0; g < 8; g++) {
    const int s0 = (blockIdx.x*8 + g)*16;
    int Lr[2];
#pragma unroll
    for (int r = 0; r < 2; r++) Lr[r] = vr[r] ? slens[s0 + si[r]] : 1;
    if (tid < 16) lens[tid] = slens[s0 + tid];
    for (int i = tid; i < 1280; i += 512) ((float*)abuf)[i] = 0.f;
    float c4[4] = {0.f, 0.f, 0.f, 0.f};
    float pf[2];
#pragma unroll
    for (int r = 0; r < 2; r++) {
      if (vr[r]) {
        int te = dir ? (Lr[r] - 1) : 0;
        te = te < 0 ? 0 : te;
        pf[r] = subwords[((size_t)(s0 + si[r])*25 + te)*50 + ki[r]];
      }
    }
    __syncthreads();

    for (int t = 0; t < 25; t++) {
#pragma unroll
      for (int r = 0; r < 2; r++)
        if (vr[r]) abuf[aslot(si[r], ki[r])] = f2bf(pf[r]);
      __syncthreads();
      if (t < 24) {
#pragma unroll
        for (int r = 0; r < 2; r++) {
          if (vr[r]) {
            int te = dir ? (Lr[r] - 2 - t) : (t + 1);
            te = te < 0 ? 0 : te;
            pf[r] = subwords[((size_t)(s0 + si[r])*25 + te)*50 + ki[r]];
          }
        }
      }

      f32x4 acc[4];
#pragma unroll
      for (int jj = 0; jj < 4; jj++) acc[jj] = (f32x4){0.f,0.f,0.f,0.f};
#pragma unroll
      for (int ks = 0; ks < 5; ks++) {
        bf16x8 af = *(const bf16x8*)&abuf[((ks*4 + lk)*16 + l16)*8];
#pragma unroll
        for (int jj = 0; jj < 4; jj++)
          if (jt[jj] < 25)
            acc[jj] = __builtin_amdgcn_mfma_f32_16x16x32_bf16(af, breg[jj][ks], acc[jj], 0, 0, 0);
      }
#pragma unroll
      for (int jj = 0; jj < 4; jj++) {
        if (jt[jj] < 25) {
#pragma unroll
          for (int r = 0; r < 4; r++)
            zs[lk*4 + r][jt[jj]*16 + l16] = acc[jj][r];
        }
      }
      __syncthreads();

#pragma unroll
      for (int jc = 0; jc < 4; jc++) {
        int idx = jc*512 + tid;
        if (idx < 1600) {
          int s = idx & 15, u = idx >> 4;
          int L = lens[s];
          if (t < L) {
            float zi = zs[s][u*4 + 0] + bs[u*4 + 0];
            float zj = zs[s][u*4 + 1] + bs[u*4 + 1];
            float zf = zs[s][u*4 + 2] + bs[u*4 + 2];
            float zo = zs[s][u*4 + 3] + bs[u*4 + 3];
            float cn = c4[jc]*sigx(zf + 1.0f) + sigx(zi)*tanx(zj);
            float hn = tanx(cn)*sigx(zo);
            c4[jc] = cn;
            bf_t hb = f2bf(hn);
            abuf[aslot(s, 50 + u)] = hb;
            if (t == L - 1) rep[(size_t)(s0 + s)*200 + dir*100 + u] = hb;
          }
        }
      }
    }
    __syncthreads();
  }
}

// ===== word_in gather (bf16, lda 512 zero-padded) =====
__global__ __launch_bounds__(128) void k_win(const float* __restrict__ tokens,
    const bf_t* __restrict__ rep, const int* __restrict__ tsub,
    bf_t* __restrict__ win){
  int row = blockIdx.x;
  int idx = tsub[row];
  const float* tsrc = tokens + (size_t)row*300;
  const bf_t* rsrc = rep + (size_t)idx*200;
  bf_t* w = win + (size_t)row*512;
  for (int i = threadIdx.x; i < 512; i += 128)
    w[i] = (i < 300) ? f2bf(tsrc[i]) : (i < 500 ? rsrc[i - 300] : (bf_t)0);
}

// ===== MFMA bf16 GEMM: zx chunk =====
__global__ __launch_bounds__(256) void k_mgemm(const bf_t* __restrict__ A, int lda, int K,
    const bf_t* __restrict__ B0, const bf_t* __restrict__ B1,
    const float* __restrict__ bp0, const float* __restrict__ bp1,
    bf_t* __restrict__ C0, bf_t* __restrict__ C1,
    const int* __restrict__ ridx1, int t0){
  const int z = blockIdx.z;
  const bf_t* B = z ? B1 : B0;
  const float* bp = z ? bp1 : bp0;
  bf_t* C = z ? C1 : C0;
  const int* ridx = z ? ridx1 : nullptr;
  __shared__ short As[4096];
  __shared__ short Bs[4096];
  const int tid = threadIdx.x;
  const int rb = blockIdx.y*128, nb = blockIdx.x*128;
  const bf_t* srcA[2]; const bf_t* srcB[2];
#pragma unroll
  for (int q = 0; q < 2; q++) {
    int s = tid + q*256;
    int row = ((s >> 6) << 4) + (s & 15), kg = (s >> 4) & 3;
    int lr = rb + row;
    int v = (t0 >= 0) ? ((lr >> 6)*256 + t0 + (lr & 63)) : lr;
    int ga = ridx ? ridx[v] : v;
    srcA[q] = A + (size_t)ga*lda + kg*8;
    srcB[q] = B + (size_t)(nb + row)*K + kg*8;
  }
  f32x4 acc[4][4];
#pragma unroll
  for (int i = 0; i < 4; i++)
#pragma unroll
    for (int j = 0; j < 4; j++) acc[i][j] = (f32x4){0.f,0.f,0.f,0.f};
  const int wid = tid >> 6, lane = tid & 63;
  const int wr = wid >> 1, wc = wid & 1;
  const int l16 = lane & 15, lk = lane >> 4;

  uint4 va0 = *(const uint4*)(srcA[0]);
  uint4 va1 = *(const uint4*)(srcA[1]);
  uint4 vb0 = *(const uint4*)(srcB[0]);
  uint4 vb1 = *(const uint4*)(srcB[1]);
  for (int kb = 0; kb < K; kb += 32) {
    __syncthreads();
    *(uint4*)&As[(size_t)tid*8] = va0;
    *(uint4*)&As[(size_t)(tid+256)*8] = va1;
    *(uint4*)&Bs[(size_t)tid*8] = vb0;
    *(uint4*)&Bs[(size_t)(tid+256)*8] = vb1;
    __syncthreads();
    if (kb + 32 < K) {
      va0 = *(const uint4*)(srcA[0] + kb + 32);
      va1 = *(const uint4*)(srcA[1] + kb + 32);
      vb0 = *(const uint4*)(srcB[0] + kb + 32);
      vb1 = *(const uint4*)(srcB[1] + kb + 32);
    }
    bf16x8 af[4], bfr[4];
#pragma unroll
    for (int f = 0; f < 4; f++) {
      af[f]  = *(const bf16x8*)&As[(((wr*4 + f)*4 + lk)*16 + l16)*8];
      bfr[f] = *(const bf16x8*)&Bs[(((wc*4 + f)*4 + lk)*16 + l16)*8];
    }
#pragma unroll
    for (int i = 0; i < 4; i++)
#pragma unroll
      for (int j = 0; j < 4; j++)
        acc[i][j] = __builtin_amdgcn_mfma_f32_16x16x32_bf16(af[i], bfr[j], acc[i][j], 0, 0, 0);
  }
#pragma unroll
  for (int i = 0; i < 4; i++) {
    int row0 = wr*64 + i*16 + lk*4;
#pragma unroll
    for (int j = 0; j < 4; j++) {
      int col = nb + wc*64 + j*16 + l16;
      float bv = bp[col];
#pragma unroll
      for (int r = 0; r < 4; r++)
        C[(size_t)(rb + row0 + r)*2048 + col] = f2bf(acc[i][j][r] + bv);
    }
  }
}

// ===== persistent recurrent chunk v8: R17 + parallel per-block step flags =====
__global__ __launch_bounds__(512) void k_chunk(
    bf_t* __restrict__ hx0, bf_t* __restrict__ hx1,
    float* __restrict__ cst, const bf_t* __restrict__ wrec,
    const bf_t* __restrict__ zxf, const bf_t* __restrict__ zxb,
    const int* __restrict__ seq_lens, bf_t* __restrict__ outp,
    unsigned* __restrict__ ctrs, int t0, int is_top){
  const int dir = is_top ? 0 : blockIdx.y;
  const int n = blockIdx.x;
  const int npb = n*128;
  unsigned* flags = ctrs + dir*256;      // 16 flags, 64B-padded (16 uints apart)
  const int tid = threadIdx.x;
  const int w = tid >> 6, lane = tid & 63;
  const int l16 = lane & 15, lk = lane >> 4;

  __shared__ __align__(16) char smem[65536];
  float (*zs)[132] = (float(*)[132])smem;

  const bf_t* B = wrec + ((size_t)dir*2048 + npb + w*16)*512;
  const bf_t* zx = (dir ? zxb : zxf);
  unsigned long long* hx08 = (unsigned long long*)hx0 + (size_t)dir*8192;
  unsigned long long* hx18 = (unsigned long long*)hx1 + (size_t)dir*8192;

  bf16x8 bfr[16];
#pragma unroll
  for (int ks = 0; ks < 16; ks++)
    bfr[ks] = *(const bf16x8*)(B + (size_t)l16*512 + ks*32 + lk*8);

  const int b = tid >> 3, q = tid & 7, u0 = q*4;
  const int len = seq_lens[b];
  const int cg0 = (npb >> 2) + u0;
  const size_t cbase = ((size_t)dir*64 + b)*512 + cg0;
  float creg[4];
#pragma unroll
  for (int it = 0; it < 4; it++) creg[it] = cst[cbase + it];
  const size_t hslot = (size_t)n*512 + b*8 + q;
  unsigned long long hpack = __hip_atomic_load(
      ((t0 & 1) ? hx18 : hx08) + hslot,
      __ATOMIC_RELAXED, __HIP_MEMORY_SCOPE_AGENT);

  for (int s = 0; s < 64; s++) {
    const int t = t0 + s;
    unsigned long long* hr8 = (t & 1) ? hx18 : hx08;
    unsigned long long* hw8 = (t & 1) ? hx08 : hx18;

    // zx prefetch (independent of h)
    const int tl = t & 63;
    uint4 zq[2];
    {
      const char* zxp = (const char*)(zx + ((size_t)(b*64 + tl))*2048 + (size_t)(npb + u0*4));
      zq[0] = *(const uint4*)zxp;
      zq[1] = *(const uint4*)(zxp + 16);
    }

    // stage all 16 blocks' h tiles (64KB) into swizzled LDS
#pragma unroll
    for (int it = 0; it < 16; it++) {
      int i = it*512 + tid;
      int nn = i >> 9, r9 = i & 511;
      int bb = r9 >> 3, qq = r9 & 7;
      unsigned long long v = __hip_atomic_load(hr8 + i,
          __ATOMIC_RELAXED, __HIP_MEMORY_SCOPE_AGENT);
      int cb = nn*64 + qq*8;
      *(unsigned long long*)&smem[bb*1024 + (((cb & ~15) ^ ((bb & 7) << 4)) | (cb & 15))] = v;
    }
    __syncthreads();

    // MFMA: A (h) from LDS, B (weights) from registers
    f32x4 acc[4];
#pragma unroll
    for (int mf = 0; mf < 4; mf++) acc[mf] = (f32x4){0.f,0.f,0.f,0.f};
#pragma unroll
    for (int ks = 0; ks < 16; ks++) {
#pragma unroll
      for (int mf = 0; mf < 4; mf++) {
        int row = mf*16 + l16;
        bf16x8 af = *(const bf16x8*)&smem[row*1024 + ((ks*64 + lk*16) ^ ((row & 7) << 4))];
        acc[mf] = __builtin_amdgcn_mfma_f32_16x16x32_bf16(af, bfr[ks], acc[mf], 0, 0, 0);
      }
    }
    __syncthreads();              // smem(h) reads done before zs overlay

    // z exchange
#pragma unroll
    for (int mf = 0; mf < 4; mf++)
#pragma unroll
      for (int r = 0; r < 4; r++)
        zs[mf*16 + lk*4 + r][w*16 + l16] = acc[mf][r];
    __syncthreads();

    // fused LSTM cell
    if (t < len) {
      const ushort* zu = (const ushort*)zq;
      bf_t hb4[4];
#pragma unroll
      for (int it = 0; it < 4; it++) {
        float zi = zs[b][(u0 + it)*4 + 0] + bf2f(zu[it*4 + 0]);
        float zj = zs[b][(u0 + it)*4 + 1] + bf2f(zu[it*4 + 1]);
        float zf = zs[b][(u0 + it)*4 + 2] + bf2f(zu[it*4 + 2]);
        float zo = zs[b][(u0 + it)*4 + 3] + bf2f(zu[it*4 + 3]);
        float cn = creg[it]*sigx(zf + 1.0f) + sigx(zi)*tanx(zj);
        float hn = tanx(cn)*sigx(zo);
        creg[it] = cn;
        hb4[it] = f2bf(hn);
      }
      hpack = *(unsigned long long*)hb4;
      if (is_top) {
        *(ushort4*)&outp[((size_t)b*256 + t)*512 + cg0] = *(ushort4*)hb4;
      } else {
        int tin = dir ? (len - 1 - t) : t;
        *(ushort4*)&outp[((size_t)b*256 + tin)*1024 + dir*512 + cg0] = *(ushort4*)hb4;
      }
    }
    __hip_atomic_store(hw8 + hslot, hpack,
                       __ATOMIC_RELAXED, __HIP_MEMORY_SCOPE_AGENT);

    // grid barrier: syncthreads drains all stores (vmcnt0), then each block
    // stores its step number to its OWN padded flag; 16 threads poll the 16
    // flags in parallel (monotonic -> no wraparound, deadlock-free).
    __syncthreads();
    if (tid == 0)
      __hip_atomic_store(flags + n*16, (unsigned)(s + 1),
                         __ATOMIC_RELAXED, __HIP_MEMORY_SCOPE_AGENT);
    if (tid < 16) {
      while (__hip_atomic_load(flags + tid*16,
                               __ATOMIC_RELAXED, __HIP_MEMORY_SCOPE_AGENT)
             < (unsigned)(s + 1)) {
        __builtin_amdgcn_s_sleep(1);
      }
    }
    __syncthreads();
  }
#pragma unroll
  for (int it = 0; it < 4; it++) cst[cbase + it] = creg[it];
}

// ===== SIMT f32-acc GEMM for the tag affine =====
__global__ __launch_bounds__(256) void k_gemm_tag(const bf_t* __restrict__ A, int lda, int K,
    const float* __restrict__ W, int ldw, const float* __restrict__ bias,
    float* __restrict__ C, int ldc){
  const int nb = blockIdx.x*64, rb = blockIdx.y*128;
  const int tid = threadIdx.x;
  const int tr = tid >> 4, tc = tid & 15;
  __shared__ float As[16][132];
  __shared__ float Bs[16][68];
  float acc[8][4];
#pragma unroll
  for (int i = 0; i < 8; i++)
#pragma unroll
    for (int j = 0; j < 4; j++) acc[i][j] = 0.f;
  const int ar = tid >> 1, ak = (tid & 1)*8;
  const int bk = tid >> 4, bn = (tid & 15)*4;
  const bf_t* arow = A + (size_t)(rb + ar)*lda;
  for (int kb = 0; kb < K; kb += 16) {
#pragma unroll
    for (int j = 0; j < 8; j++)
      As[ak + j][ar] = bf2f(arow[kb + ak + j]);
    const float* wp = W + (size_t)(kb + bk)*ldw + nb + bn;
    Bs[bk][bn] = wp[0]; Bs[bk][bn+1] = wp[1]; Bs[bk][bn+2] = wp[2]; Bs[bk][bn+3] = wp[3];
    __syncthreads();
#pragma unroll
    for (int kk = 0; kk < 16; kk++) {
      float4 a0 = *(const float4*)&As[kk][tr*8];
      float4 a1 = *(const float4*)&As[kk][tr*8 + 4];
      float4 bq = *(const float4*)&Bs[kk][tc*4];
      float av[8] = {a0.x,a0.y,a0.z,a0.w,a1.x,a1.y,a1.z,a1.w};
      float bv[4] = {bq.x,bq.y,bq.z,bq.w};
#pragma unroll
      for (int i = 0; i < 8; i++)
#pragma unroll
        for (int j = 0; j < 4; j++) acc[i][j] += av[i]*bv[j];
    }
    __syncthreads();
  }
  float4 bb = *(const float4*)&bias[nb + tc*4];
  float bias4[4] = {bb.x, bb.y, bb.z, bb.w};
#pragma unroll
  for (int i = 0; i < 8; i++) {
    size_t row = rb + tr*8 + i;
#pragma unroll
    for (int j = 0; j < 4; j++)
      C[row*(size_t)ldc + nb + tc*4 + j] = acc[i][j] + bias4[j];
  }
}

// ===== BN stats =====
__global__ __launch_bounds__(512) void k_bnstats(const bf_t* __restrict__ out2,
    float* __restrict__ gsum, float* __restrict__ gsq){
  int c = threadIdx.x;
  int r0 = blockIdx.x*256;
  float s = 0.f, q = 0.f;
  for (int i = 0; i < 256; i++) {
    float v = bf2f(out2[(size_t)(r0 + i)*512 + c]);
    s += v; q += v*v;
  }
  atomicAdd(&gsum[c], s);
  atomicAdd(&gsq[c], q);
}

// ===== fold BN into tag affine =====
__global__ __launch_bounds__(512) void k_bnfin(const float* __restrict__ gsum,
    const float* __restrict__ gsq, const float* __restrict__ gamma,
    const float* __restrict__ beta, const float* __restrict__ wt,
    const float* __restrict__ bt, float* __restrict__ wtp, float* __restrict__ btp){
  __shared__ float a_s[512], d_s[512];
  int c = threadIdx.x;
  float mean = gsum[c] * (1.0f/16384.0f);
  float var  = gsq[c]  * (1.0f/16384.0f) - mean*mean;
  float a = gamma[c] * rsqrtf(var + 1e-3f);
  a_s[c] = a;
  d_s[c] = beta[c] - mean*a;
  __syncthreads();
  for (int i = c; i < 512*64; i += 512) wtp[i] = a_s[i >> 6] * wt[i];
  if (c < 64) {
    float acc = bt[c];
    for (int cc = 0; cc < 512; cc++) acc += d_s[cc] * wt[cc*64 + c];
    btp[c] = acc;
  }
}

extern "C" void kernel_launch(void* const* d_in, const int* in_sizes, int n_in,
                              void* d_out, int out_size, void* d_ws, size_t ws_size,
                              hipStream_t stream) {
  const float* subwords = (const float*)d_in[0];
  const float* tokens   = (const float*)d_in[1];
  const int*   tsub     = (const int*)d_in[2];
  const int*   sublens  = (const int*)d_in[3];
  const int*   seqlens  = (const int*)d_in[4];
  const float* wcf = (const float*)d_in[5];
  const float* bcf = (const float*)d_in[6];
  const float* wcb = (const float*)d_in[7];
  const float* bcb = (const float*)d_in[8];
  const float* wwf = (const float*)d_in[9];
  const float* bwf = (const float*)d_in[10];
  const float* wwb = (const float*)d_in[11];
  const float* bwb = (const float*)d_in[12];
  const float* wo  = (const float*)d_in[13];
  const float* bo  = (const float*)d_in[14];
  const float* gma = (const float*)d_in[15];
  const float* bta = (const float*)d_in[16];
  const float* wt  = (const float*)d_in[17];
  const float* btb = (const float*)d_in[18];
  float* out = (float*)d_out;

  char* ws = (char*)d_ws;
  size_t off = 0;
  auto alc = [&](size_t bytes) -> void* {
    void* p = ws + off;
    off += (bytes + 255) & ~(size_t)255;
    return p;
  };
  bf_t* REP   = (bf_t*)alc(16384ull*200*2);
  bf_t* WIN   = (bf_t*)alc(16384ull*512*2);
  int*  RIDXB = (int*) alc(16384ull*4);
  bf_t* ZXF   = (bf_t*)alc(4096ull*2048*2);
  bf_t* ZXB   = (bf_t*)alc(4096ull*2048*2);
  bf_t* HID   = (bf_t*)alc(16384ull*1024*2);
  // state block: HX dbufs, c states, bn sums, flags (8 launches x 2KB)
  const size_t STATB = 131072 + 131072 + 65536 + 65536 + 262144 + 131072
                     + 2048 + 2048 + 16384;
  char* STAT0 = (char*)alc(STATB);
  bf_t* HXW0 = (bf_t*)STAT0;
  bf_t* HXW1 = (bf_t*)(STAT0 + 131072);
  bf_t* HXT0 = (bf_t*)(STAT0 + 262144);
  bf_t* HXT1 = (bf_t*)(STAT0 + 327680);
  float* CSW = (float*)(STAT0 + 393216);
  float* CST = (float*)(STAT0 + 655360);
  float* GSUM = (float*)(STAT0 + 786432);
  float* GSQ  = (float*)(STAT0 + 788480);
  unsigned* CTRS = (unsigned*)(STAT0 + 790528);   // 16KB: 8 launches x 512 uints
  float* WTP  = (float*)alc(512ull*64*4);
  float* BTP  = (float*)alc(64*4);
  bf_t* WCT  = (bf_t*)alc(2ull*400*160*2);
  bf_t* WRG  = (bf_t*)alc(2ull*2048*512*2);
  bf_t* WOG  = (bf_t*)alc(2048ull*512*2);
  bf_t* WXG  = (bf_t*)alc(2ull*2048*512*2);
  bf_t* WXT  = (bf_t*)alc(2048ull*1024*2);
  float* BPF = (float*)alc(2048*4);
  float* BPB = (float*)alc(2048*4);
  float* BPT = (float*)alc(2048*4);
  bf_t* ZXT  = ZXF;
  bf_t* OUT2 = ZXB;
  if (off > ws_size) {
    k_dbg<<<1, 1, 0, stream>>>(out, (unsigned)(ws_size >> 20));
    return;
  }

  hipMemsetAsync(HID, 0, 16384ull*1024*2, stream);
  hipMemsetAsync(STAT0, 0, STATB, stream);

  k_prep_charm<<<500, 256, 0, stream>>>(wcf, wcb, WCT);
  k_prep_wrec<<<8192, 256, 0, stream>>>(wwf, wwb, WRG);
  k_prep_trec<<<4096, 256, 0, stream>>>(wo, WOG);
  k_prep_wx<<<8192, 256, 0, stream>>>(wwf, wwb, WXG);
  k_prep_wxt<<<8192, 256, 0, stream>>>(wo, WXT);
  k_prep_bias<<<8, 256, 0, stream>>>(bwf, bwb, bo, BPF, BPB, BPT);
  k_ridx<<<64, 256, 0, stream>>>(seqlens, RIDXB);

  k_charm<<<dim3(128, 2), 512, 0, stream>>>(subwords, sublens, WCT, bcf, bcb, REP);
  k_win<<<16384, 128, 0, stream>>>(tokens, REP, tsub, WIN);

  for (int ch = 0; ch < 4; ch++) {
    k_mgemm<<<dim3(16, 32, 2), 256, 0, stream>>>(WIN, 512, 512,
        WXG, WXG + 2048ull*512, BPF, BPB, ZXF, ZXB, RIDXB, ch*64);
    k_chunk<<<dim3(16, 2), 512, 0, stream>>>(HXW0, HXW1, CSW, WRG, ZXF, ZXB,
                                             seqlens, HID, CTRS + ch*512, ch*64, 0);
  }

  hipMemsetAsync(OUT2, 0, 16384ull*512*2, stream);
  for (int ch = 0; ch < 4; ch++) {
    k_mgemm<<<dim3(16, 32, 1), 256, 0, stream>>>(HID, 1024, 1024,
        WXT, nullptr, BPT, nullptr, ZXT, nullptr, nullptr, ch*64);
    k_chunk<<<dim3(16, 1), 512, 0, stream>>>(HXT0, HXT1, CST, WOG, ZXT, nullptr,
                                             seqlens, OUT2, CTRS + (4 + ch)*512, ch*64, 1);
  }

  k_bnstats<<<64, 512, 0, stream>>>(OUT2, GSUM, GSQ);
  k_bnfin<<<1, 512, 0, stream>>>(GSUM, GSQ, gma, bta, wt, btb, WTP, BTP);
  k_gemm_tag<<<dim3(1, 128, 1), 256, 0, stream>>>(OUT2, 512, 512, WTP, 64, BTP, out, 64);
}

// Round 20
// 4786.032 us; speedup vs baseline: 1.0079x; 1.0079x over previous
//
#include <hip/hip_runtime.h>
#include <cstdint>
#include <cstddef>

// Round 20: final latency micro-bundle on R19 base (4824us; chunks 8x528us,
// step ~8.3us, MfmaUtil 1.3% => pure latency chain). (1) publish-first: h'
// store -> drain-sync -> flag store, outp stores moved POST-publish (drain
// during poll; kernel-end release covers them). (2) hard-spin poll (no
// s_sleep; 16 pollers on 16 distinct lines, read-shared).

typedef unsigned short bf_t;
typedef __attribute__((ext_vector_type(8))) short bf16x8;
typedef __attribute__((ext_vector_type(4))) float f32x4;

#define DEVI __device__ __forceinline__
DEVI float bf2f(bf_t u){ return __uint_as_float(((unsigned)u)<<16); }
DEVI bf_t  f2bf(float f){ unsigned u=__float_as_uint(f); return (bf_t)((u + 0x7FFFu + ((u>>16)&1u))>>16); }
DEVI float sigx(float x){ return __builtin_amdgcn_rcpf(1.0f + __builtin_amdgcn_exp2f(-1.44269504f*x)); }
DEVI float tanx(float x){ return 2.0f*__builtin_amdgcn_rcpf(1.0f + __builtin_amdgcn_exp2f(-2.88539008f*x)) - 1.0f; }

__global__ void k_dbg(float* out, unsigned mb){ out[0] = (float)mb; }

// ===== weight prep =====
__global__ __launch_bounds__(256) void k_prep_charm(const float* __restrict__ wcf,
    const float* __restrict__ wcb, bf_t* __restrict__ wct){
  int i = blockIdx.x*256 + threadIdx.x;
  if (i >= 2*400*160) return;
  int kk = i % 160; int r = i / 160;
  int np = r % 400; int dir = r / 400;
  int u = np >> 2, g = np & 3;
  const float* w = dir ? wcb : wcf;
  wct[i] = (kk < 150) ? f2bf(w[kk*400 + g*100 + u]) : (bf_t)0;
}
__global__ __launch_bounds__(256) void k_prep_wrec(const float* __restrict__ wwf,
    const float* __restrict__ wwb, bf_t* __restrict__ wrg){
  int i = blockIdx.x*256 + threadIdx.x;
  if (i >= 2*2048*512) return;
  int k = i & 511; int np = (i >> 9) & 2047; int dir = i >> 20;
  int c = np >> 2, g = np & 3;
  const float* w = dir ? wwb : wwf;
  wrg[i] = f2bf(w[(size_t)(500 + k)*2048 + g*512 + c]);
}
__global__ __launch_bounds__(256) void k_prep_trec(const float* __restrict__ wo,
    bf_t* __restrict__ wog){
  int i = blockIdx.x*256 + threadIdx.x;
  if (i >= 2048*512) return;
  int k = i & 511; int np = i >> 9;
  int c = np >> 2, g = np & 3;
  wog[i] = f2bf(wo[(size_t)(1024 + k)*2048 + g*512 + c]);
}
__global__ __launch_bounds__(256) void k_prep_wx(const float* __restrict__ wwf,
    const float* __restrict__ wwb, bf_t* __restrict__ wx){
  int i = blockIdx.x*256 + threadIdx.x;
  if (i >= 2*2048*512) return;
  int k = i & 511; int r = i >> 9;
  int np = r & 2047; int dir = r >> 11;
  int c = np >> 2, g = np & 3;
  const float* w = dir ? wwb : wwf;
  wx[i] = (k < 500) ? f2bf(w[(size_t)k*2048 + g*512 + c]) : (bf_t)0;
}
__global__ __launch_bounds__(256) void k_prep_wxt(const float* __restrict__ wo,
    bf_t* __restrict__ wxt){
  int i = blockIdx.x*256 + threadIdx.x;
  if (i >= 2048*1024) return;
  int k = i & 1023; int np = i >> 10;
  int c = np >> 2, g = np & 3;
  wxt[i] = f2bf(wo[(size_t)k*2048 + g*512 + c]);
}
__global__ __launch_bounds__(256) void k_prep_bias(const float* __restrict__ bwf,
    const float* __restrict__ bwb, const float* __restrict__ bo,
    float* __restrict__ bpf, float* __restrict__ bpb, float* __restrict__ bpt){
  int np = blockIdx.x*256 + threadIdx.x;
  if (np >= 2048) return;
  int c = np >> 2, g = np & 3;
  bpf[np] = bwf[g*512 + c];
  bpb[np] = bwb[g*512 + c];
  bpt[np] = bo[g*512 + c];
}
__global__ __launch_bounds__(256) void k_ridx(const int* __restrict__ lens,
    int* __restrict__ ridxb){
  int b = blockIdx.x, t = threadIdx.x;
  int L = lens[b];
  int tin = (t < L) ? (L - 1 - t) : t;
  ridxb[b*256 + t] = b*256 + tin;
}

// ===== char BiLSTM v3: persistent, MFMA, weights in registers =====
DEVI int aslot(int s, int kk){
  return (((kk >> 5)*4 + ((kk >> 3) & 3))*16 + s)*8 + (kk & 7);
}
__global__ __launch_bounds__(512) void k_charm(const float* __restrict__ subwords,
    const int* __restrict__ slens, const bf_t* __restrict__ wct,
    const float* __restrict__ bcf, const float* __restrict__ bcb,
    bf_t* __restrict__ rep){
  const int dir = blockIdx.y;
  const int tid = threadIdx.x;
  const int w = tid >> 6, lane = tid & 63;
  const int l16 = lane & 15, lk = lane >> 4;

  __shared__ __align__(16) bf_t abuf[2560];
  __shared__ float zs[16][409];
  __shared__ float bs[400];
  __shared__ int lens[16];

  {
    const float* bc = dir ? bcb : bcf;
    for (int i = tid; i < 400; i += 512) bs[i] = bc[(i & 3)*100 + (i >> 2)];
  }

  const bf_t* wctd = wct + (size_t)dir*400*160;
  int jt[4];
  bf16x8 breg[4][5];
#pragma unroll
  for (int jj = 0; jj < 4; jj++) {
    int j = w + jj*8; jt[jj] = j;
    int js = (j < 25) ? j : 0;
#pragma unroll
    for (int ks = 0; ks < 5; ks++)
      breg[jj][ks] = *(const bf16x8*)(wctd + (size_t)(js*16 + l16)*160 + ks*32 + lk*8);
  }

  int si[2], ki[2]; bool vr[2];
#pragma unroll
  for (int r = 0; r < 2; r++) {
    int i = tid + r*512;
    vr[r] = (i < 800);
    si[r] = vr[r] ? (i / 50) : 0;
    ki[r] = vr[r] ? (i - si[r]*50) : 0;
  }

  for (int g = 0; g < 8; g++) {
    const int s0 = (blockIdx.x*8 + g)*16;
    int Lr[2];
#pragma unroll
    for (int r = 0; r < 2; r++) Lr[r] = vr[r] ? slens[s0 + si[r]] : 1;
    if (tid < 16) lens[tid] = slens[s0 + tid];
    for (int i = tid; i < 1280; i += 512) ((float*)abuf)[i] = 0.f;
    float c4[4] = {0.f, 0.f, 0.f, 0.f};
    float pf[2];
#pragma unroll
    for (int r = 0; r < 2; r++) {
      if (vr[r]) {
        int te = dir ? (Lr[r] - 1) : 0;
        te = te < 0 ? 0 : te;
        pf[r] = subwords[((size_t)(s0 + si[r])*25 + te)*50 + ki[r]];
      }
    }
    __syncthreads();

    for (int t = 0; t < 25; t++) {
#pragma unroll
      for (int r = 0; r < 2; r++)
        if (vr[r]) abuf[aslot(si[r], ki[r])] = f2bf(pf[r]);
      __syncthreads();
      if (t < 24) {
#pragma unroll
        for (int r = 0; r < 2; r++) {
          if (vr[r]) {
            int te = dir ? (Lr[r] - 2 - t) : (t + 1);
            te = te < 0 ? 0 : te;
            pf[r] = subwords[((size_t)(s0 + si[r])*25 + te)*50 + ki[r]];
          }
        }
      }

      f32x4 acc[4];
#pragma unroll
      for (int jj = 0; jj < 4; jj++) acc[jj] = (f32x4){0.f,0.f,0.f,0.f};
#pragma unroll
      for (int ks = 0; ks < 5; ks++) {
        bf16x8 af = *(const bf16x8*)&abuf[((ks*4 + lk)*16 + l16)*8];
#pragma unroll
        for (int jj = 0; jj < 4; jj++)
          if (jt[jj] < 25)
            acc[jj] = __builtin_amdgcn_mfma_f32_16x16x32_bf16(af, breg[jj][ks], acc[jj], 0, 0, 0);
      }
#pragma unroll
      for (int jj = 0; jj < 4; jj++) {
        if (jt[jj] < 25) {
#pragma unroll
          for (int r = 0; r < 4; r++)
            zs[lk*4 + r][jt[jj]*16 + l16] = acc[jj][r];
        }
      }
      __syncthreads();

#pragma unroll
      for (int jc = 0; jc < 4; jc++) {
        int idx = jc*512 + tid;
        if (idx < 1600) {
          int s = idx & 15, u = idx >> 4;
          int L = lens[s];
          if (t < L) {
            float zi = zs[s][u*4 + 0] + bs[u*4 + 0];
            float zj = zs[s][u*4 + 1] + bs[u*4 + 1];
            float zf = zs[s][u*4 + 2] + bs[u*4 + 2];
            float zo = zs[s][u*4 + 3] + bs[u*4 + 3];
            float cn = c4[jc]*sigx(zf + 1.0f) + sigx(zi)*tanx(zj);
            float hn = tanx(cn)*sigx(zo);
            c4[jc] = cn;
            bf_t hb = f2bf(hn);
            abuf[aslot(s, 50 + u)] = hb;
            if (t == L - 1) rep[(size_t)(s0 + s)*200 + dir*100 + u] = hb;
          }
        }
      }
    }
    __syncthreads();
  }
}

// ===== word_in gather (bf16, lda 512 zero-padded) =====
__global__ __launch_bounds__(128) void k_win(const float* __restrict__ tokens,
    const bf_t* __restrict__ rep, const int* __restrict__ tsub,
    bf_t* __restrict__ win){
  int row = blockIdx.x;
  int idx = tsub[row];
  const float* tsrc = tokens + (size_t)row*300;
  const bf_t* rsrc = rep + (size_t)idx*200;
  bf_t* w = win + (size_t)row*512;
  for (int i = threadIdx.x; i < 512; i += 128)
    w[i] = (i < 300) ? f2bf(tsrc[i]) : (i < 500 ? rsrc[i - 300] : (bf_t)0);
}

// ===== MFMA bf16 GEMM: zx chunk =====
__global__ __launch_bounds__(256) void k_mgemm(const bf_t* __restrict__ A, int lda, int K,
    const bf_t* __restrict__ B0, const bf_t* __restrict__ B1,
    const float* __restrict__ bp0, const float* __restrict__ bp1,
    bf_t* __restrict__ C0, bf_t* __restrict__ C1,
    const int* __restrict__ ridx1, int t0){
  const int z = blockIdx.z;
  const bf_t* B = z ? B1 : B0;
  const float* bp = z ? bp1 : bp0;
  bf_t* C = z ? C1 : C0;
  const int* ridx = z ? ridx1 : nullptr;
  __shared__ short As[4096];
  __shared__ short Bs[4096];
  const int tid = threadIdx.x;
  const int rb = blockIdx.y*128, nb = blockIdx.x*128;
  const bf_t* srcA[2]; const bf_t* srcB[2];
#pragma unroll
  for (int q = 0; q < 2; q++) {
    int s = tid + q*256;
    int row = ((s >> 6) << 4) + (s & 15), kg = (s >> 4) & 3;
    int lr = rb + row;
    int v = (t0 >= 0) ? ((lr >> 6)*256 + t0 + (lr & 63)) : lr;
    int ga = ridx ? ridx[v] : v;
    srcA[q] = A + (size_t)ga*lda + kg*8;
    srcB[q] = B + (size_t)(nb + row)*K + kg*8;
  }
  f32x4 acc[4][4];
#pragma unroll
  for (int i = 0; i < 4; i++)
#pragma unroll
    for (int j = 0; j < 4; j++) acc[i][j] = (f32x4){0.f,0.f,0.f,0.f};
  const int wid = tid >> 6, lane = tid & 63;
  const int wr = wid >> 1, wc = wid & 1;
  const int l16 = lane & 15, lk = lane >> 4;

  uint4 va0 = *(const uint4*)(srcA[0]);
  uint4 va1 = *(const uint4*)(srcA[1]);
  uint4 vb0 = *(const uint4*)(srcB[0]);
  uint4 vb1 = *(const uint4*)(srcB[1]);
  for (int kb = 0; kb < K; kb += 32) {
    __syncthreads();
    *(uint4*)&As[(size_t)tid*8] = va0;
    *(uint4*)&As[(size_t)(tid+256)*8] = va1;
    *(uint4*)&Bs[(size_t)tid*8] = vb0;
    *(uint4*)&Bs[(size_t)(tid+256)*8] = vb1;
    __syncthreads();
    if (kb + 32 < K) {
      va0 = *(const uint4*)(srcA[0] + kb + 32);
      va1 = *(const uint4*)(srcA[1] + kb + 32);
      vb0 = *(const uint4*)(srcB[0] + kb + 32);
      vb1 = *(const uint4*)(srcB[1] + kb + 32);
    }
    bf16x8 af[4], bfr[4];
#pragma unroll
    for (int f = 0; f < 4; f++) {
      af[f]  = *(const bf16x8*)&As[(((wr*4 + f)*4 + lk)*16 + l16)*8];
      bfr[f] = *(const bf16x8*)&Bs[(((wc*4 + f)*4 + lk)*16 + l16)*8];
    }
#pragma unroll
    for (int i = 0; i < 4; i++)
#pragma unroll
      for (int j = 0; j < 4; j++)
        acc[i][j] = __builtin_amdgcn_mfma_f32_16x16x32_bf16(af[i], bfr[j], acc[i][j], 0, 0, 0);
  }
#pragma unroll
  for (int i = 0; i < 4; i++) {
    int row0 = wr*64 + i*16 + lk*4;
#pragma unroll
    for (int j = 0; j < 4; j++) {
      int col = nb + wc*64 + j*16 + l16;
      float bv = bp[col];
#pragma unroll
      for (int r = 0; r < 4; r++)
        C[(size_t)(rb + row0 + r)*2048 + col] = f2bf(acc[i][j][r] + bv);
    }
  }
}

// ===== persistent recurrent chunk v9: publish-first barrier, hard-spin poll =====
__global__ __launch_bounds__(512) void k_chunk(
    bf_t* __restrict__ hx0, bf_t* __restrict__ hx1,
    float* __restrict__ cst, const bf_t* __restrict__ wrec,
    const bf_t* __restrict__ zxf, const bf_t* __restrict__ zxb,
    const int* __restrict__ seq_lens, bf_t* __restrict__ outp,
    unsigned* __restrict__ ctrs, int t0, int is_top){
  const int dir = is_top ? 0 : blockIdx.y;
  const int n = blockIdx.x;
  const int npb = n*128;
  unsigned* flags = ctrs + dir*256;      // 16 flags, 64B-padded
  const int tid = threadIdx.x;
  const int w = tid >> 6, lane = tid & 63;
  const int l16 = lane & 15, lk = lane >> 4;

  __shared__ __align__(16) char smem[65536];
  float (*zs)[132] = (float(*)[132])smem;

  const bf_t* B = wrec + ((size_t)dir*2048 + npb + w*16)*512;
  const bf_t* zx = (dir ? zxb : zxf);
  unsigned long long* hx08 = (unsigned long long*)hx0 + (size_t)dir*8192;
  unsigned long long* hx18 = (unsigned long long*)hx1 + (size_t)dir*8192;

  bf16x8 bfr[16];
#pragma unroll
  for (int ks = 0; ks < 16; ks++)
    bfr[ks] = *(const bf16x8*)(B + (size_t)l16*512 + ks*32 + lk*8);

  const int b = tid >> 3, q = tid & 7, u0 = q*4;
  const int len = seq_lens[b];
  const int cg0 = (npb >> 2) + u0;
  const size_t cbase = ((size_t)dir*64 + b)*512 + cg0;
  float creg[4];
#pragma unroll
  for (int it = 0; it < 4; it++) creg[it] = cst[cbase + it];
  const size_t hslot = (size_t)n*512 + b*8 + q;
  unsigned long long hpack = __hip_atomic_load(
      ((t0 & 1) ? hx18 : hx08) + hslot,
      __ATOMIC_RELAXED, __HIP_MEMORY_SCOPE_AGENT);

  for (int s = 0; s < 64; s++) {
    const int t = t0 + s;
    unsigned long long* hr8 = (t & 1) ? hx18 : hx08;
    unsigned long long* hw8 = (t & 1) ? hx08 : hx18;

    // zx prefetch (independent of h)
    const int tl = t & 63;
    uint4 zq[2];
    {
      const char* zxp = (const char*)(zx + ((size_t)(b*64 + tl))*2048 + (size_t)(npb + u0*4));
      zq[0] = *(const uint4*)zxp;
      zq[1] = *(const uint4*)(zxp + 16);
    }

    // stage all 16 blocks' h tiles (64KB) into swizzled LDS
#pragma unroll
    for (int it = 0; it < 16; it++) {
      int i = it*512 + tid;
      int nn = i >> 9, r9 = i & 511;
      int bb = r9 >> 3, qq = r9 & 7;
      unsigned long long v = __hip_atomic_load(hr8 + i,
          __ATOMIC_RELAXED, __HIP_MEMORY_SCOPE_AGENT);
      int cb = nn*64 + qq*8;
      *(unsigned long long*)&smem[bb*1024 + (((cb & ~15) ^ ((bb & 7) << 4)) | (cb & 15))] = v;
    }
    __syncthreads();

    // MFMA: A (h) from LDS, B (weights) from registers
    f32x4 acc[4];
#pragma unroll
    for (int mf = 0; mf < 4; mf++) acc[mf] = (f32x4){0.f,0.f,0.f,0.f};
#pragma unroll
    for (int ks = 0; ks < 16; ks++) {
#pragma unroll
      for (int mf = 0; mf < 4; mf++) {
        int row = mf*16 + l16;
        bf16x8 af = *(const bf16x8*)&smem[row*1024 + ((ks*64 + lk*16) ^ ((row & 7) << 4))];
        acc[mf] = __builtin_amdgcn_mfma_f32_16x16x32_bf16(af, bfr[ks], acc[mf], 0, 0, 0);
      }
    }
    __syncthreads();              // smem(h) reads done before zs overlay

    // z exchange
#pragma unroll
    for (int mf = 0; mf < 4; mf++)
#pragma unroll
      for (int r = 0; r < 4; r++)
        zs[mf*16 + lk*4 + r][w*16 + l16] = acc[mf][r];
    __syncthreads();

    // fused LSTM cell (registers); h' store FIRST (critical path)
    bf_t hb4[4];
    const bool act = (t < len);
    if (act) {
      const ushort* zu = (const ushort*)zq;
#pragma unroll
      for (int it = 0; it < 4; it++) {
        float zi = zs[b][(u0 + it)*4 + 0] + bf2f(zu[it*4 + 0]);
        float zj = zs[b][(u0 + it)*4 + 1] + bf2f(zu[it*4 + 1]);
        float zf = zs[b][(u0 + it)*4 + 2] + bf2f(zu[it*4 + 2]);
        float zo = zs[b][(u0 + it)*4 + 3] + bf2f(zu[it*4 + 3]);
        float cn = creg[it]*sigx(zf + 1.0f) + sigx(zi)*tanx(zj);
        float hn = tanx(cn)*sigx(zo);
        creg[it] = cn;
        hb4[it] = f2bf(hn);
      }
      hpack = *(unsigned long long*)hb4;
    }
    __hip_atomic_store(hw8 + hslot, hpack,
                       __ATOMIC_RELAXED, __HIP_MEMORY_SCOPE_AGENT);

    // drain h' (per-wave vmcnt0 + barrier), then publish flag
    __syncthreads();
    if (tid == 0)
      __hip_atomic_store(flags + n*16, (unsigned)(s + 1),
                         __ATOMIC_RELAXED, __HIP_MEMORY_SCOPE_AGENT);
    // outp store post-publish (drains during poll window / kernel-end release)
    if (act) {
      if (is_top) {
        *(ushort4*)&outp[((size_t)b*256 + t)*512 + cg0] = *(ushort4*)hb4;
      } else {
        int tin = dir ? (len - 1 - t) : t;
        *(ushort4*)&outp[((size_t)b*256 + tin)*1024 + dir*512 + cg0] = *(ushort4*)hb4;
      }
    }
    // hard-spin poll: 16 threads x 16 distinct 64B lines
    if (tid < 16) {
      while (__hip_atomic_load(flags + tid*16,
                               __ATOMIC_RELAXED, __HIP_MEMORY_SCOPE_AGENT)
             < (unsigned)(s + 1)) { }
    }
    __syncthreads();
  }
#pragma unroll
  for (int it = 0; it < 4; it++) cst[cbase + it] = creg[it];
}

// ===== SIMT f32-acc GEMM for the tag affine =====
__global__ __launch_bounds__(256) void k_gemm_tag(const bf_t* __restrict__ A, int lda, int K,
    const float* __restrict__ W, int ldw, const float* __restrict__ bias,
    float* __restrict__ C, int ldc){
  const int nb = blockIdx.x*64, rb = blockIdx.y*128;
  const int tid = threadIdx.x;
  const int tr = tid >> 4, tc = tid & 15;
  __shared__ float As[16][132];
  __shared__ float Bs[16][68];
  float acc[8][4];
#pragma unroll
  for (int i = 0; i < 8; i++)
#pragma unroll
    for (int j = 0; j < 4; j++) acc[i][j] = 0.f;
  const int ar = tid >> 1, ak = (tid & 1)*8;
  const int bk = tid >> 4, bn = (tid & 15)*4;
  const bf_t* arow = A + (size_t)(rb + ar)*lda;
  for (int kb = 0; kb < K; kb += 16) {
#pragma unroll
    for (int j = 0; j < 8; j++)
      As[ak + j][ar] = bf2f(arow[kb + ak + j]);
    const float* wp = W + (size_t)(kb + bk)*ldw + nb + bn;
    Bs[bk][bn] = wp[0]; Bs[bk][bn+1] = wp[1]; Bs[bk][bn+2] = wp[2]; Bs[bk][bn+3] = wp[3];
    __syncthreads();
#pragma unroll
    for (int kk = 0; kk < 16; kk++) {
      float4 a0 = *(const float4*)&As[kk][tr*8];
      float4 a1 = *(const float4*)&As[kk][tr*8 + 4];
      float4 bq = *(const float4*)&Bs[kk][tc*4];
      float av[8] = {a0.x,a0.y,a0.z,a0.w,a1.x,a1.y,a1.z,a1.w};
      float bv[4] = {bq.x,bq.y,bq.z,bq.w};
#pragma unroll
      for (int i = 0; i < 8; i++)
#pragma unroll
        for (int j = 0; j < 4; j++) acc[i][j] += av[i]*bv[j];
    }
    __syncthreads();
  }
  float4 bb = *(const float4*)&bias[nb + tc*4];
  float bias4[4] = {bb.x, bb.y, bb.z, bb.w};
#pragma unroll
  for (int i = 0; i < 8; i++) {
    size_t row = rb + tr*8 + i;
#pragma unroll
    for (int j = 0; j < 4; j++)
      C[row*(size_t)ldc + nb + tc*4 + j] = acc[i][j] + bias4[j];
  }
}

// ===== BN stats =====
__global__ __launch_bounds__(512) void k_bnstats(const bf_t* __restrict__ out2,
    float* __restrict__ gsum, float* __restrict__ gsq){
  int c = threadIdx.x;
  int r0 = blockIdx.x*256;
  float s = 0.f, q = 0.f;
  for (int i = 0; i < 256; i++) {
    float v = bf2f(out2[(size_t)(r0 + i)*512 + c]);
    s += v; q += v*v;
  }
  atomicAdd(&gsum[c], s);
  atomicAdd(&gsq[c], q);
}

// ===== fold BN into tag affine =====
__global__ __launch_bounds__(512) void k_bnfin(const float* __restrict__ gsum,
    const float* __restrict__ gsq, const float* __restrict__ gamma,
    const float* __restrict__ beta, const float* __restrict__ wt,
    const float* __restrict__ bt, float* __restrict__ wtp, float* __restrict__ btp){
  __shared__ float a_s[512], d_s[512];
  int c = threadIdx.x;
  float mean = gsum[c] * (1.0f/16384.0f);
  float var  = gsq[c]  * (1.0f/16384.0f) - mean*mean;
  float a = gamma[c] * rsqrtf(var + 1e-3f);
  a_s[c] = a;
  d_s[c] = beta[c] - mean*a;
  __syncthreads();
  for (int i = c; i < 512*64; i += 512) wtp[i] = a_s[i >> 6] * wt[i];
  if (c < 64) {
    float acc = bt[c];
    for (int cc = 0; cc < 512; cc++) acc += d_s[cc] * wt[cc*64 + c];
    btp[c] = acc;
  }
}

extern "C" void kernel_launch(void* const* d_in, const int* in_sizes, int n_in,
                              void* d_out, int out_size, void* d_ws, size_t ws_size,
                              hipStream_t stream) {
  const float* subwords = (const float*)d_in[0];
  const float* tokens   = (const float*)d_in[1];
  const int*   tsub     = (const int*)d_in[2];
  const int*   sublens  = (const int*)d_in[3];
  const int*   seqlens  = (const int*)d_in[4];
  const float* wcf = (const float*)d_in[5];
  const float* bcf = (const float*)d_in[6];
  const float* wcb = (const float*)d_in[7];
  const float* bcb = (const float*)d_in[8];
  const float* wwf = (const float*)d_in[9];
  const float* bwf = (const float*)d_in[10];
  const float* wwb = (const float*)d_in[11];
  const float* bwb = (const float*)d_in[12];
  const float* wo  = (const float*)d_in[13];
  const float* bo  = (const float*)d_in[14];
  const float* gma = (const float*)d_in[15];
  const float* bta = (const float*)d_in[16];
  const float* wt  = (const float*)d_in[17];
  const float* btb = (const float*)d_in[18];
  float* out = (float*)d_out;

  char* ws = (char*)d_ws;
  size_t off = 0;
  auto alc = [&](size_t bytes) -> void* {
    void* p = ws + off;
    off += (bytes + 255) & ~(size_t)255;
    return p;
  };
  bf_t* REP   = (bf_t*)alc(16384ull*200*2);
  bf_t* WIN   = (bf_t*)alc(16384ull*512*2);
  int*  RIDXB = (int*) alc(16384ull*4);
  bf_t* ZXF   = (bf_t*)alc(4096ull*2048*2);
  bf_t* ZXB   = (bf_t*)alc(4096ull*2048*2);
  bf_t* HID   = (bf_t*)alc(16384ull*1024*2);
  const size_t STATB = 131072 + 131072 + 65536 + 65536 + 262144 + 131072
                     + 2048 + 2048 + 16384;
  char* STAT0 = (char*)alc(STATB);
  bf_t* HXW0 = (bf_t*)STAT0;
  bf_t* HXW1 = (bf_t*)(STAT0 + 131072);
  bf_t* HXT0 = (bf_t*)(STAT0 + 262144);
  bf_t* HXT1 = (bf_t*)(STAT0 + 327680);
  float* CSW = (float*)(STAT0 + 393216);
  float* CST = (float*)(STAT0 + 655360);
  float* GSUM = (float*)(STAT0 + 786432);
  float* GSQ  = (float*)(STAT0 + 788480);
  unsigned* CTRS = (unsigned*)(STAT0 + 790528);
  float* WTP  = (float*)alc(512ull*64*4);
  float* BTP  = (float*)alc(64*4);
  bf_t* WCT  = (bf_t*)alc(2ull*400*160*2);
  bf_t* WRG  = (bf_t*)alc(2ull*2048*512*2);
  bf_t* WOG  = (bf_t*)alc(2048ull*512*2);
  bf_t* WXG  = (bf_t*)alc(2ull*2048*512*2);
  bf_t* WXT  = (bf_t*)alc(2048ull*1024*2);
  float* BPF = (float*)alc(2048*4);
  float* BPB = (float*)alc(2048*4);
  float* BPT = (float*)alc(2048*4);
  bf_t* ZXT  = ZXF;
  bf_t* OUT2 = ZXB;
  if (off > ws_size) {
    k_dbg<<<1, 1, 0, stream>>>(out, (unsigned)(ws_size >> 20));
    return;
  }

  hipMemsetAsync(HID, 0, 16384ull*1024*2, stream);
  hipMemsetAsync(STAT0, 0, STATB, stream);

  k_prep_charm<<<500, 256, 0, stream>>>(wcf, wcb, WCT);
  k_prep_wrec<<<8192, 256, 0, stream>>>(wwf, wwb, WRG);
  k_prep_trec<<<4096, 256, 0, stream>>>(wo, WOG);
  k_prep_wx<<<8192, 256, 0, stream>>>(wwf, wwb, WXG);
  k_prep_wxt<<<8192, 256, 0, stream>>>(wo, WXT);
  k_prep_bias<<<8, 256, 0, stream>>>(bwf, bwb, bo, BPF, BPB, BPT);
  k_ridx<<<64, 256, 0, stream>>>(seqlens, RIDXB);

  k_charm<<<dim3(128, 2), 512, 0, stream>>>(subwords, sublens, WCT, bcf, bcb, REP);
  k_win<<<16384, 128, 0, stream>>>(tokens, REP, tsub, WIN);

  for (int ch = 0; ch < 4; ch++) {
    k_mgemm<<<dim3(16, 32, 2), 256, 0, stream>>>(WIN, 512, 512,
        WXG, WXG + 2048ull*512, BPF, BPB, ZXF, ZXB, RIDXB, ch*64);
    k_chunk<<<dim3(16, 2), 512, 0, stream>>>(HXW0, HXW1, CSW, WRG, ZXF, ZXB,
                                             seqlens, HID, CTRS + ch*512, ch*64, 0);
  }

  hipMemsetAsync(OUT2, 0, 16384ull*512*2, stream);
  for (int ch = 0; ch < 4; ch++) {
    k_mgemm<<<dim3(16, 32, 1), 256, 0, stream>>>(HID, 1024, 1024,
        WXT, nullptr, BPT, nullptr, ZXT, nullptr, nullptr, ch*64);
    k_chunk<<<dim3(16, 1), 512, 0, stream>>>(HXT0, HXT1, CST, WOG, ZXT, nullptr,
                                             seqlens, OUT2, CTRS + (4 + ch)*512, ch*64, 1);
  }

  k_bnstats<<<64, 512, 0, stream>>>(OUT2, GSUM, GSQ);
  k_bnfin<<<1, 512, 0, stream>>>(GSUM, GSQ, gma, bta, wt, btb, WTP, BTP);
  k_gemm_tag<<<dim3(1, 128, 1), 256, 0, stream>>>(OUT2, 512, 512, WTP, 64, BTP, out, 64);
}